// Round 5
// baseline (241.418 us; speedup 1.0000x reference)
//
#include <hip/hip_runtime.h>
#include <hip/hip_bf16.h>

#define NBATCH 256
#define NT 512
#define ND 256
#define NROWS (NBATCH * NT)

typedef __attribute__((ext_vector_type(8))) short short8;
typedef __attribute__((ext_vector_type(4))) float floatx4;

__device__ __forceinline__ unsigned short f2bf(float x) {
    // round-to-nearest-even fp32 -> bf16
    unsigned int u = __float_as_uint(x);
    u += 0x7FFFu + ((u >> 16) & 1u);
    return (unsigned short)(u >> 16);
}

// prep: W fp32 [D,D] (e,d) -> bf16 chunks in MFMA-FRAG ORDER.
// chunk g (16B = 8 bf16) = nb*512 + s*64 + q*16 + m
//   <-> W[e = nb*16 + m][k = q*8 + s*32 .. +8]
// So in scores_kernel, frag (nb,s) for lane = q*16+m is chunk nb*512+s*64+lane:
// lane-linear => fully coalesced 1KB wave loads, no LDS needed.
__global__ void __launch_bounds__(256) prep_kernel(
    const float* __restrict__ W, unsigned short* __restrict__ wf)
{
    int g  = blockIdx.x * 256 + threadIdx.x;   // 8192 chunks
    int m  = g & 15, q = (g >> 4) & 3, s = (g >> 6) & 7, nb = g >> 9;
    const float* src = W + (nb * 16 + m) * ND + q * 8 + s * 32;
    float4 f0 = *(const float4*)src;
    float4 f1 = *(const float4*)(src + 4);
    short8 v;
    v[0] = (short)f2bf(f0.x); v[1] = (short)f2bf(f0.y);
    v[2] = (short)f2bf(f0.z); v[3] = (short)f2bf(f0.w);
    v[4] = (short)f2bf(f1.x); v[5] = (short)f2bf(f1.y);
    v[6] = (short)f2bf(f1.z); v[7] = (short)f2bf(f1.w);
    *(short8*)(wf + (long)g * 8) = v;
}

// scores[bt] = sum_e tanh(sum_d ip[bt,d]*W[e,d] + bias[e]) * ctx[e]
// 1024 blocks x 256 thr (4 waves), NO barriers, NO LDS tile:
// wave owns 32 rows (2 A-tiles, register-resident), W frags loaded
// coalesced from frag-ordered wf (L1/L2-hot: 128KB read identically by all waves).
__global__ void __launch_bounds__(256, 3) scores_kernel(
    const float* __restrict__ ip,             // [B*T, D] fp32
    const unsigned short* __restrict__ wf,    // frag-ordered W bf16
    const float* __restrict__ bias,           // [D] fp32
    const float* __restrict__ ctx,            // [D] fp32
    float* __restrict__ scores)               // [B*T] fp32
{
    const int tid  = threadIdx.x;
    const int lane = tid & 63;
    const int wv   = tid >> 6;        // wave 0..3
    const int m    = lane & 15;       // A row / W e-col within tile
    const int q    = lane >> 4;       // k-quad
    const long row0 = (long)blockIdx.x * 128 + wv * 32;

    // A fragments: 32 rows/wave, fp32 -> bf16, register-resident (64 VGPR)
    short8 a[2][8];
#pragma unroll
    for (int tile = 0; tile < 2; ++tile) {
        const float* ar = ip + (row0 + tile * 16 + m) * ND + q * 8;
#pragma unroll
        for (int s = 0; s < 8; ++s) {
            float4 f0 = *(const float4*)(ar + s * 32);
            float4 f1 = *(const float4*)(ar + s * 32 + 4);
            short8 v;
            v[0] = (short)f2bf(f0.x); v[1] = (short)f2bf(f0.y);
            v[2] = (short)f2bf(f0.z); v[3] = (short)f2bf(f0.w);
            v[4] = (short)f2bf(f1.x); v[5] = (short)f2bf(f1.y);
            v[6] = (short)f2bf(f1.z); v[7] = (short)f2bf(f1.w);
            a[tile][s] = v;
        }
    }

    float sc0[4] = {0.f, 0.f, 0.f, 0.f};
    float sc1[4] = {0.f, 0.f, 0.f, 0.f};
    const short8* wchunks = (const short8*)wf;

#pragma unroll 1
    for (int nb = 0; nb < 16; ++nb) {
        const int e = nb * 16 + m;
        const short8* wp = wchunks + nb * 512 + lane;  // lane-linear: coalesced 1KB/instr
        short8 w[8];
#pragma unroll
        for (int s = 0; s < 8; ++s) w[s] = wp[s * 64];
        floatx4 acc0 = {0.f, 0.f, 0.f, 0.f};
        floatx4 acc1 = {0.f, 0.f, 0.f, 0.f};
#pragma unroll
        for (int s = 0; s < 8; ++s) {
            acc0 = __builtin_amdgcn_mfma_f32_16x16x32_bf16(a[0][s], w[s], acc0, 0, 0, 0);
            acc1 = __builtin_amdgcn_mfma_f32_16x16x32_bf16(a[1][s], w[s], acc1, 0, 0, 0);
        }
        const float be  = bias[e];          // 1KB table, L1-hot
        const float ce  = ctx[e];
        const float ce2 = ce + ce;
#pragma unroll
        for (int r = 0; r < 4; ++r) {       // acc[r] = D[row=q*4+r][col=m]
            float x0 = acc0[r] + be;
            float x1 = acc1[r] + be;
            // tanh(x)*ce = ce - ce2 * rcp(exp(2x)+1);  saturates correctly at +-inf
            float t0 = __builtin_amdgcn_rcpf(__expf(x0 + x0) + 1.f);
            float t1 = __builtin_amdgcn_rcpf(__expf(x1 + x1) + 1.f);
            sc0[r] = __builtin_fmaf(-ce2, t0, sc0[r] + ce);
            sc1[r] = __builtin_fmaf(-ce2, t1, sc1[r] + ce);
        }
    }

    // sum over 16 e-cols spread across lanes sharing a quad (xor lane bits 0..3)
#pragma unroll
    for (int off = 8; off >= 1; off >>= 1) {
#pragma unroll
        for (int r = 0; r < 4; ++r) {
            sc0[r] += __shfl_xor(sc0[r], off, 64);
            sc1[r] += __shfl_xor(sc1[r], off, 64);
        }
    }
    if (m == 0) {
#pragma unroll
        for (int r = 0; r < 4; ++r) {
            scores[row0 + q * 4 + r]      = sc0[r];
            scores[row0 + 16 + q * 4 + r] = sc1[r];
        }
    }
}

// wsum: block (b, dquad of 64 floats). In-block softmax over scores[b,:],
// then out[b, d] = sum_t attn[t] * ip[b,t,d] for d in the 64-float slice.
__global__ void __launch_bounds__(256) wsum_kernel(
    const float* __restrict__ ip,       // [B,T,D] fp32
    const float* __restrict__ scores,   // [B,T] fp32
    float* __restrict__ out)            // [B,D] fp32
{
    __shared__ float attn_s[NT];
    __shared__ float red[8];
    __shared__ float partial[16][64];

    const int b  = blockIdx.x >> 2;
    const int dq = blockIdx.x & 3;      // d-slice: [dq*64, dq*64+64)
    const int tid  = threadIdx.x;
    const int lane = tid & 63;
    const int wv   = tid >> 6;          // wave 0..3

    // softmax: each thread handles scores tid and tid+256
    float s0 = scores[(long)b * NT + tid];
    float s1 = scores[(long)b * NT + tid + 256];
    float mx = fmaxf(s0, s1);
#pragma unroll
    for (int off = 32; off >= 1; off >>= 1) mx = fmaxf(mx, __shfl_xor(mx, off, 64));
    if (lane == 0) red[wv] = mx;
    __syncthreads();
    mx = fmaxf(fmaxf(red[0], red[1]), fmaxf(red[2], red[3]));
    float e0 = __expf(s0 - mx), e1 = __expf(s1 - mx);
    float sm = e0 + e1;
#pragma unroll
    for (int off = 32; off >= 1; off >>= 1) sm += __shfl_xor(sm, off, 64);
    __syncthreads();                    // red max-reads done before rewrite
    if (lane == 0) red[4 + wv] = sm;
    __syncthreads();
    sm = red[4] + red[5] + red[6] + red[7];
    float inv = 1.f / sm;
    attn_s[tid]       = e0 * inv;
    attn_s[tid + 256] = e1 * inv;
    __syncthreads();

    // weighted sum: thread = (dg float4 in slice: 0..15, t-slice ts: 0..15 of 32 t)
    const int dg = tid & 15;
    const int ts = tid >> 4;
    const float4* base = (const float4*)(ip + (long)b * NT * ND + dq * 64) + dg;
    float a0 = 0.f, a1 = 0.f, a2 = 0.f, a3 = 0.f;
#pragma unroll 8
    for (int t = ts * 32; t < ts * 32 + 32; ++t) {
        float w = attn_s[t];
        float4 v = base[t * 64];        // row stride = 64 float4
        a0 += w * v.x; a1 += w * v.y; a2 += w * v.z; a3 += w * v.w;
    }
    partial[ts][dg * 4 + 0] = a0;
    partial[ts][dg * 4 + 1] = a1;
    partial[ts][dg * 4 + 2] = a2;
    partial[ts][dg * 4 + 3] = a3;
    __syncthreads();
    if (tid < 64) {
        float r = 0.f;
#pragma unroll
        for (int i = 0; i < 16; ++i) r += partial[i][tid];
        out[(long)b * ND + dq * 64 + tid] = r;
    }
}

extern "C" void kernel_launch(void* const* d_in, const int* in_sizes, int n_in,
                              void* d_out, int out_size, void* d_ws, size_t ws_size,
                              hipStream_t stream) {
    const float* ip   = (const float*)d_in[0];
    const float* W    = (const float*)d_in[1];
    const float* bias = (const float*)d_in[2];
    const float* ctx  = (const float*)d_in[3];

    unsigned short* wf = (unsigned short*)d_ws;   // 128 KB, frag-ordered W
    float* scores = (float*)((char*)d_ws + ND * ND * sizeof(unsigned short)); // 512 KB

    prep_kernel<<<32, 256, 0, stream>>>(W, wf);
    scores_kernel<<<NROWS / 128, 256, 0, stream>>>(ip, wf, bias, ctx, scores);
    wsum_kernel<<<NBATCH * 4, 256, 0, stream>>>(ip, scores, (float*)d_out);
}

// Round 6
// 233.319 us; speedup vs baseline: 1.0347x; 1.0347x over previous
//
#include <hip/hip_runtime.h>
#include <hip/hip_bf16.h>

#define NBATCH 256
#define NT 512
#define ND 256
#define NROWS (NBATCH * NT)

typedef __attribute__((ext_vector_type(8))) short short8;
typedef __attribute__((ext_vector_type(4))) float floatx4;

__device__ __forceinline__ unsigned short f2bf(float x) {
    // round-to-nearest-even fp32 -> bf16
    unsigned int u = __float_as_uint(x);
    u += 0x7FFFu + ((u >> 16) & 1u);
    return (unsigned short)(u >> 16);
}

// prep: W fp32 [D,D] (e,d) -> bf16 chunks in MFMA-FRAG ORDER.
// chunk g (16B = 8 bf16) = nb*512 + s*64 + q*16 + m
//   <-> W[e = nb*16 + m][k = q*8 + s*32 .. +8]
__global__ void __launch_bounds__(256) prep_kernel(
    const float* __restrict__ W, unsigned short* __restrict__ wf)
{
    int g  = blockIdx.x * 256 + threadIdx.x;   // 8192 chunks
    int m  = g & 15, q = (g >> 4) & 3, s = (g >> 6) & 7, nb = g >> 9;
    const float* src = W + (nb * 16 + m) * ND + q * 8 + s * 32;
    float4 f0 = *(const float4*)src;
    float4 f1 = *(const float4*)(src + 4);
    short8 v;
    v[0] = (short)f2bf(f0.x); v[1] = (short)f2bf(f0.y);
    v[2] = (short)f2bf(f0.z); v[3] = (short)f2bf(f0.w);
    v[4] = (short)f2bf(f1.x); v[5] = (short)f2bf(f1.y);
    v[6] = (short)f2bf(f1.z); v[7] = (short)f2bf(f1.w);
    *(short8*)(wf + (long)g * 8) = v;
}

// scores[bt] = sum_e tanh(sum_d ip[bt,d]*W[e,d] + bias[e]) * ctx[e]
// 1024 blocks x 256 thr (4 waves). W staged to LDS once per BLOCK in
// 32KB quarters: staging is chunk-linear (coalesced 16B/lane), frag reads
// are lane-linear ds_read_b128 (conflict-free). Cuts W L1-line traffic
// from 33k to ~2k lines/CU (the R5 bottleneck).
__global__ void __launch_bounds__(256, 3) scores_kernel(
    const float* __restrict__ ip,             // [B*T, D] fp32
    const unsigned short* __restrict__ wf,    // frag-ordered W bf16
    const float* __restrict__ bias,           // [D] fp32
    const float* __restrict__ ctx,            // [D] fp32
    float* __restrict__ scores)               // [B*T] fp32
{
    __shared__ __align__(16) char wsm[32768];   // one W quarter, frag order
    __shared__ float bias_s[ND];
    __shared__ float ctx_s[ND];

    const int tid  = threadIdx.x;
    const int lane = tid & 63;
    const int wv   = tid >> 6;        // wave 0..3
    const int m    = lane & 15;       // A row / W e-col within tile
    const int q    = lane >> 4;       // k-quad
    const long row0 = (long)blockIdx.x * 128 + wv * 32;

    bias_s[tid] = bias[tid];
    ctx_s[tid]  = ctx[tid];

    // A fragments: 32 rows/wave, fp32 -> bf16, register-resident (64 VGPR)
    short8 a[2][8];
#pragma unroll
    for (int tile = 0; tile < 2; ++tile) {
        const float* ar = ip + (row0 + tile * 16 + m) * ND + q * 8;
#pragma unroll
        for (int s = 0; s < 8; ++s) {
            float4 f0 = *(const float4*)(ar + s * 32);
            float4 f1 = *(const float4*)(ar + s * 32 + 4);
            short8 v;
            v[0] = (short)f2bf(f0.x); v[1] = (short)f2bf(f0.y);
            v[2] = (short)f2bf(f0.z); v[3] = (short)f2bf(f0.w);
            v[4] = (short)f2bf(f1.x); v[5] = (short)f2bf(f1.y);
            v[6] = (short)f2bf(f1.z); v[7] = (short)f2bf(f1.w);
            a[tile][s] = v;
        }
    }

    float sc0[4] = {0.f, 0.f, 0.f, 0.f};
    float sc1[4] = {0.f, 0.f, 0.f, 0.f};
    const short8* wchunks = (const short8*)wf;
    short8* wsm16 = (short8*)wsm;

#pragma unroll 1
    for (int stage = 0; stage < 4; ++stage) {
        if (stage) __syncthreads();             // prior quarter's reads done
        // copy 2048 chunks (32KB), chunk-linear: coalesced global + conflict-free LDS
#pragma unroll
        for (int u = 0; u < 8; ++u) {
            int c = u * 256 + tid;
            wsm16[c] = wchunks[stage * 2048 + c];
        }
        __syncthreads();

#pragma unroll 1
        for (int nbl = 0; nbl < 4; ++nbl) {
            const int e = (stage * 4 + nbl) * 16 + m;
            const short8* wp = wsm16 + nbl * 512 + lane;   // lane-linear b128
            short8 w[8];
#pragma unroll
            for (int s = 0; s < 8; ++s) w[s] = wp[s * 64];
            floatx4 acc0 = {0.f, 0.f, 0.f, 0.f};
            floatx4 acc1 = {0.f, 0.f, 0.f, 0.f};
#pragma unroll
            for (int s = 0; s < 8; ++s) {
                acc0 = __builtin_amdgcn_mfma_f32_16x16x32_bf16(a[0][s], w[s], acc0, 0, 0, 0);
                acc1 = __builtin_amdgcn_mfma_f32_16x16x32_bf16(a[1][s], w[s], acc1, 0, 0, 0);
            }
            const float be  = bias_s[e];
            const float ce  = ctx_s[e];
            const float ce2 = ce + ce;
#pragma unroll
            for (int r = 0; r < 4; ++r) {       // acc[r] = D[row=q*4+r][col=m]
                float x0 = acc0[r] + be;
                float x1 = acc1[r] + be;
                // tanh(x)*ce = ce - ce2 * rcp(exp(2x)+1)
                float t0 = __builtin_amdgcn_rcpf(__expf(x0 + x0) + 1.f);
                float t1 = __builtin_amdgcn_rcpf(__expf(x1 + x1) + 1.f);
                sc0[r] = __builtin_fmaf(-ce2, t0, sc0[r] + ce);
                sc1[r] = __builtin_fmaf(-ce2, t1, sc1[r] + ce);
            }
        }
    }

    // sum over 16 e-cols spread across lanes sharing a quad (xor lane bits 0..3)
#pragma unroll
    for (int off = 8; off >= 1; off >>= 1) {
#pragma unroll
        for (int r = 0; r < 4; ++r) {
            sc0[r] += __shfl_xor(sc0[r], off, 64);
            sc1[r] += __shfl_xor(sc1[r], off, 64);
        }
    }
    if (m == 0) {
#pragma unroll
        for (int r = 0; r < 4; ++r) {
            scores[row0 + q * 4 + r]      = sc0[r];
            scores[row0 + 16 + q * 4 + r] = sc1[r];
        }
    }
}

// wsum: block (b, dquad of 64 floats). In-block softmax over scores[b,:],
// then out[b, d] = sum_t attn[t] * ip[b,t,d] for d in the 64-float slice.
__global__ void __launch_bounds__(256) wsum_kernel(
    const float* __restrict__ ip,       // [B,T,D] fp32
    const float* __restrict__ scores,   // [B,T] fp32
    float* __restrict__ out)            // [B,D] fp32
{
    __shared__ float attn_s[NT];
    __shared__ float red[8];
    __shared__ float partial[16][64];

    const int b  = blockIdx.x >> 2;
    const int dq = blockIdx.x & 3;      // d-slice: [dq*64, dq*64+64)
    const int tid  = threadIdx.x;
    const int lane = tid & 63;
    const int wv   = tid >> 6;          // wave 0..3

    // softmax: each thread handles scores tid and tid+256
    float s0 = scores[(long)b * NT + tid];
    float s1 = scores[(long)b * NT + tid + 256];
    float mx = fmaxf(s0, s1);
#pragma unroll
    for (int off = 32; off >= 1; off >>= 1) mx = fmaxf(mx, __shfl_xor(mx, off, 64));
    if (lane == 0) red[wv] = mx;
    __syncthreads();
    mx = fmaxf(fmaxf(red[0], red[1]), fmaxf(red[2], red[3]));
    float e0 = __expf(s0 - mx), e1 = __expf(s1 - mx);
    float sm = e0 + e1;
#pragma unroll
    for (int off = 32; off >= 1; off >>= 1) sm += __shfl_xor(sm, off, 64);
    __syncthreads();                    // red max-reads done before rewrite
    if (lane == 0) red[4 + wv] = sm;
    __syncthreads();
    sm = red[4] + red[5] + red[6] + red[7];
    float inv = 1.f / sm;
    attn_s[tid]       = e0 * inv;
    attn_s[tid + 256] = e1 * inv;
    __syncthreads();

    // weighted sum: thread = (dg float4 in slice: 0..15, t-slice ts: 0..15 of 32 t)
    const int dg = tid & 15;
    const int ts = tid >> 4;
    const float4* base = (const float4*)(ip + (long)b * NT * ND + dq * 64) + dg;
    float a0 = 0.f, a1 = 0.f, a2 = 0.f, a3 = 0.f;
#pragma unroll 8
    for (int t = ts * 32; t < ts * 32 + 32; ++t) {
        float w = attn_s[t];
        float4 v = base[t * 64];        // row stride = 64 float4
        a0 += w * v.x; a1 += w * v.y; a2 += w * v.z; a3 += w * v.w;
    }
    partial[ts][dg * 4 + 0] = a0;
    partial[ts][dg * 4 + 1] = a1;
    partial[ts][dg * 4 + 2] = a2;
    partial[ts][dg * 4 + 3] = a3;
    __syncthreads();
    if (tid < 64) {
        float r = 0.f;
#pragma unroll
        for (int i = 0; i < 16; ++i) r += partial[i][tid];
        out[(long)b * ND + dq * 64 + tid] = r;
    }
}

extern "C" void kernel_launch(void* const* d_in, const int* in_sizes, int n_in,
                              void* d_out, int out_size, void* d_ws, size_t ws_size,
                              hipStream_t stream) {
    const float* ip   = (const float*)d_in[0];
    const float* W    = (const float*)d_in[1];
    const float* bias = (const float*)d_in[2];
    const float* ctx  = (const float*)d_in[3];

    unsigned short* wf = (unsigned short*)d_ws;   // 128 KB, frag-ordered W
    float* scores = (float*)((char*)d_ws + ND * ND * sizeof(unsigned short)); // 512 KB

    prep_kernel<<<32, 256, 0, stream>>>(W, wf);
    scores_kernel<<<NROWS / 128, 256, 0, stream>>>(ip, wf, bias, ctx, scores);
    wsum_kernel<<<NBATCH * 4, 256, 0, stream>>>(ip, scores, (float*)d_out);
}